// Round 8
// baseline (382.971 us; speedup 1.0000x reference)
//
#include <hip/hip_runtime.h>
#include <math.h>

#define N_NODES 20000
#define N_EDGES 320000
#define EP (N_EDGES + N_NODES)   // with self loops
#define HEADS 5

__device__ __forceinline__ float lrelu(float s) { return (s > 0.f) ? s : 0.2f * s; }

// ---------------- CSR build ----------------
__global__ void count_deg_k(const int* __restrict__ ei, int* __restrict__ deg) {
  int e = blockIdx.x * blockDim.x + threadIdx.x;
  if (e >= EP) return;
  int dst = (e < N_EDGES) ? ei[N_EDGES + e] : (e - N_EDGES);
  atomicAdd(&deg[dst], 1);
}

__global__ __launch_bounds__(256) void scan1_k(const int* __restrict__ deg,
                                               int* __restrict__ offs,
                                               int* __restrict__ bsum) {
  __shared__ int buf[256];
  int tid = threadIdx.x, i = blockIdx.x * 256 + tid;
  int v = (i < N_NODES) ? deg[i] : 0;
  buf[tid] = v;
  __syncthreads();
  for (int o = 1; o < 256; o <<= 1) {
    int t = (tid >= o) ? buf[tid - o] : 0;
    __syncthreads();
    buf[tid] += t;
    __syncthreads();
  }
  if (i < N_NODES) offs[i] = buf[tid] - v;   // block-local exclusive
  if (tid == 255) bsum[blockIdx.x] = buf[255];
}

__global__ __launch_bounds__(128) void scan2_k(int* __restrict__ bsum, int nb) {
  __shared__ int buf[128];
  int tid = threadIdx.x;
  int v = (tid < nb) ? bsum[tid] : 0;
  buf[tid] = v;
  __syncthreads();
  for (int o = 1; o < 128; o <<= 1) {
    int t = (tid >= o) ? buf[tid - o] : 0;
    __syncthreads();
    buf[tid] += t;
    __syncthreads();
  }
  if (tid < nb) bsum[tid] = buf[tid] - v;    // exclusive
}

__global__ void scan3_k(int* __restrict__ offs, const int* __restrict__ bsum) {
  int i = blockIdx.x * 256 + threadIdx.x;
  if (i < N_NODES) offs[i] += bsum[blockIdx.x];
  if (i == 0) offs[N_NODES] = EP;
}

__global__ void scatter_k(const int* __restrict__ ei, const int* __restrict__ offs,
                          int* __restrict__ cursor, int* __restrict__ ssrc) {
  int e = blockIdx.x * blockDim.x + threadIdx.x;
  if (e >= EP) return;
  int src, dst;
  if (e < N_EDGES) { src = ei[e]; dst = ei[N_EDGES + e]; }
  else             { src = e - N_EDGES; dst = src; }
  int pos = atomicAdd(&cursor[dst], 1);
  ssrc[offs[dst] + pos] = src;
}

// ---------------- pack [W2 | W3] into Wc[64][320] ----------------
__global__ void pack23_k(const float* __restrict__ W2, const float* __restrict__ W3,
                         float* __restrict__ Wc) {
  int t = blockIdx.x * blockDim.x + threadIdx.x;   // 64*160
  if (t >= 64 * 160) return;
  int k = t / 160, j = t % 160;
  Wc[k * 320 + j]       = W2[t];
  Wc[k * 320 + 160 + j] = W3[t];
}

// ---------------- fp32 tiled GEMM + fused attention-sums epilogue ----------------
// C[M,N] = A[M,K] @ B[K,N]; BM=BN=64, BK=32, 256 threads, 4x4/thread.
// Double-buffered LDS, register prefetch, ONE barrier per K-iteration.
// Grid is (N/64, M/64): blocks sharing an A-tile are consecutive (L2 locality).
// C written in 64-col slices: C[((bn/64)*M + r)*64 + (c-bn)].
// Epilogue: per CH-col unit u (= global_col/CH), as_out[u*M+r] = row . att_s[u].
template <int CH>
__global__ __launch_bounds__(256) void sgemm_fused_k(
    const float* __restrict__ A, const float* __restrict__ B, float* __restrict__ C,
    const float* __restrict__ attAs, const float* __restrict__ attAd,
    const float* __restrict__ attBs, const float* __restrict__ attBd,
    float* __restrict__ as_out, float* __restrict__ ad_out,
    int M, int N, int K) {
  __shared__ float As[2][32][65];
  __shared__ float Bs[2][32][68];
  int bm = blockIdx.y * 64, bn = blockIdx.x * 64;
  int tid = threadIdx.x;
  int tr = (tid / 16) * 4;
  int tc = (tid % 16) * 4;
  float acc[4][4] = {};

  // per-thread load coordinates (2 float4 each for A and B per tile)
  int mA[2], kqA[2], kB[2], nqB[2];
#pragma unroll
  for (int i = 0; i < 2; i++) {
    int idx = tid + i * 256;
    mA[i] = idx >> 3;  kqA[i] = idx & 7;    // A tile: 64 rows x 8 float4
    kB[i] = idx >> 4;  nqB[i] = idx & 15;   // B tile: 32 rows x 16 float4
  }

  float4 pa[2], pb[2];
  int nit = K >> 5;

  // prologue: tile 0 -> regs -> LDS[0]
#pragma unroll
  for (int i = 0; i < 2; i++) {
    int row = bm + mA[i];
    pa[i] = (row < M) ? *(const float4*)&A[(size_t)row * K + kqA[i] * 4]
                      : make_float4(0.f, 0.f, 0.f, 0.f);
    pb[i] = *(const float4*)&B[(size_t)kB[i] * N + bn + nqB[i] * 4];
  }
#pragma unroll
  for (int i = 0; i < 2; i++) {
    As[0][kqA[i] * 4 + 0][mA[i]] = pa[i].x;
    As[0][kqA[i] * 4 + 1][mA[i]] = pa[i].y;
    As[0][kqA[i] * 4 + 2][mA[i]] = pa[i].z;
    As[0][kqA[i] * 4 + 3][mA[i]] = pa[i].w;
    *(float4*)&Bs[0][kB[i]][nqB[i] * 4] = pb[i];
  }
  __syncthreads();

  for (int it = 0; it < nit; ++it) {
    int cur = it & 1;
    if (it + 1 < nit) {
      int k0 = (it + 1) << 5;
#pragma unroll
      for (int i = 0; i < 2; i++) {
        int row = bm + mA[i];
        pa[i] = (row < M) ? *(const float4*)&A[(size_t)row * K + k0 + kqA[i] * 4]
                          : make_float4(0.f, 0.f, 0.f, 0.f);
        pb[i] = *(const float4*)&B[(size_t)(k0 + kB[i]) * N + bn + nqB[i] * 4];
      }
    }
#pragma unroll
    for (int k = 0; k < 32; k++) {
      float av[4], bv[4];
#pragma unroll
      for (int j = 0; j < 4; j++) { av[j] = As[cur][k][tr + j]; bv[j] = Bs[cur][k][tc + j]; }
#pragma unroll
      for (int i = 0; i < 4; i++)
#pragma unroll
        for (int j = 0; j < 4; j++) acc[i][j] += av[i] * bv[j];
    }
    if (it + 1 < nit) {
      int nb_ = cur ^ 1;
#pragma unroll
      for (int i = 0; i < 2; i++) {
        As[nb_][kqA[i] * 4 + 0][mA[i]] = pa[i].x;
        As[nb_][kqA[i] * 4 + 1][mA[i]] = pa[i].y;
        As[nb_][kqA[i] * 4 + 2][mA[i]] = pa[i].z;
        As[nb_][kqA[i] * 4 + 3][mA[i]] = pa[i].w;
        *(float4*)&Bs[nb_][kB[i]][nqB[i] * 4] = pb[i];
      }
      __syncthreads();
    }
  }

  int gs = bn >> 6;
#pragma unroll
  for (int i = 0; i < 4; i++) {
    int r = bm + tr + i;
    if (r < M)
      *(float4*)&C[((size_t)gs * M + r) * 64 + tc] =
          make_float4(acc[i][0], acc[i][1], acc[i][2], acc[i][3]);
  }

  // fused attention sums
  int u  = (bn + tc) / CH;
  int cc = tc % CH;
  const float* avs; const float* avd;
  if (CH == 64)       { avs = attAs + u * 64 + cc;           avd = attAd + u * 64 + cc; }
  else if (u < HEADS) { avs = attAs + u * 32 + cc;           avd = attAd + u * 32 + cc; }
  else                { avs = attBs + (u - HEADS) * 32 + cc; avd = attBd + (u - HEADS) * 32 + cc; }
  float w_s[4], w_d[4];
#pragma unroll
  for (int j = 0; j < 4; j++) { w_s[j] = avs[j]; w_d[j] = avd[j]; }
#pragma unroll
  for (int i = 0; i < 4; i++) {
    float ps = acc[i][0] * w_s[0] + acc[i][1] * w_s[1] + acc[i][2] * w_s[2] + acc[i][3] * w_s[3];
    float pd = acc[i][0] * w_d[0] + acc[i][1] * w_d[1] + acc[i][2] * w_d[2] + acc[i][3] * w_d[3];
#pragma unroll
    for (int o = 1; o < CH / 4; o <<= 1) {
      ps += __shfl_xor(ps, o);
      pd += __shfl_xor(pd, o);
    }
    int r = bm + tr + i;
    if (((tid & ((CH / 4) - 1)) == 0) && r < M) {
      as_out[(size_t)u * M + r] = ps;
      ad_out[(size_t)u * M + r] = pd;
    }
  }
}

// ---------------- layer 1: block per node, 5 waves (wave = head), LDS reduce ----------------
// __shfl broadcasts stay OUTSIDE divergent guards (ds_bpermute from inactive lane
// is undefined on CDNA — was the R3-R5 bug).
__global__ __launch_bounds__(320) void agg1_k(const int* __restrict__ offs,
                                              const int* __restrict__ ssrc,
                                              const float* __restrict__ a_s,
                                              const float* __restrict__ a_d,
                                              const float* __restrict__ xw,
                                              const float* __restrict__ b1,
                                              float* __restrict__ h1) {
  int n = blockIdx.x;
  int u = threadIdx.x >> 6;          // wave = head/unit
  int lane = threadIdx.x & 63;
  int off = offs[n], end = offs[n + 1];
  int deg = end - off;
  float ad = a_d[(size_t)u * N_NODES + n];
  const float* asl = a_s + (size_t)u * N_NODES;
  const float* xb  = xw + (size_t)u * N_NODES * 64;
  int g = lane >> 4, q = lane & 15;
  float ax = 0.f, ay = 0.f, az = 0.f, aw = 0.f;

  if (deg <= 64) {
    int s = 0;
    float e = -1e30f;
    if (lane < deg) { s = ssrc[off + lane]; e = lrelu(asl[s] + ad); }
    float m = e;
#pragma unroll
    for (int o = 32; o > 0; o >>= 1) m = fmaxf(m, __shfl_xor(m, o));
    float p = (lane < deg) ? __expf(e - m) : 0.f;
    float den = p;
#pragma unroll
    for (int o = 32; o > 0; o >>= 1) den += __shfl_xor(den, o);
    float alpha = p * (1.f / (den + 1e-16f));

    for (int base = 0; base < deg; base += 4) {
      int ee = base + g;
      bool ok = ee < deg;
      int es = ok ? ee : 0;             // clamp: all lanes + sources active
      float al = __shfl(alpha, es);
      int   sv = __shfl(s, es);
      if (ok) {
        float4 v = *(const float4*)&xb[(size_t)sv * 64 + q * 4];
        ax += al * v.x; ay += al * v.y; az += al * v.z; aw += al * v.w;
      }
    }
  } else {
    float m = -1e30f;
    for (int i = off + lane; i < end; i += 64) m = fmaxf(m, lrelu(asl[ssrc[i]] + ad));
#pragma unroll
    for (int o = 32; o > 0; o >>= 1) m = fmaxf(m, __shfl_xor(m, o));
    float den = 0.f;
    for (int i = off + lane; i < end; i += 64) den += __expf(lrelu(asl[ssrc[i]] + ad) - m);
#pragma unroll
    for (int o = 32; o > 0; o >>= 1) den += __shfl_xor(den, o);
    float inv = 1.f / (den + 1e-16f);
    for (int base = off; base < end; base += 4) {
      int e = base + g;
      if (e < end) {
        int sv = ssrc[e];
        float al = __expf(lrelu(asl[sv] + ad) - m) * inv;
        float4 v = *(const float4*)&xb[(size_t)sv * 64 + q * 4];
        ax += al * v.x; ay += al * v.y; az += al * v.z; aw += al * v.w;
      }
    }
  }

#pragma unroll
  for (int o = 16; o < 64; o <<= 1) {
    ax += __shfl_xor(ax, o); ay += __shfl_xor(ay, o);
    az += __shfl_xor(az, o); aw += __shfl_xor(aw, o);
  }

  __shared__ float sacc[HEADS][64];
  if (g == 0) *(float4*)&sacc[u][q * 4] = make_float4(ax, ay, az, aw);
  __syncthreads();
  if (threadIdx.x < 64) {
    int t = threadIdx.x;
    float v = sacc[0][t] + sacc[1][t] + sacc[2][t] + sacc[3][t] + sacc[4][t];
    v = v * 0.2f + b1[t];
    h1[(size_t)n * 64 + t] = fmaxf(v, 0.f);
  }
}

// ---------------- layers 2+3: block per node, 5 waves (wave = pair 2g,2g+1) ----------------
// slice g: cols 0-31 = unit 2g, cols 32-63 = unit 2g+1. Units 0-4 -> layer2, 5-9 -> layer3.
__global__ __launch_bounds__(320) void agg23_k(const int* __restrict__ offs,
                                               const int* __restrict__ ssrc,
                                               const float* __restrict__ a_s,
                                               const float* __restrict__ a_d,
                                               const float* __restrict__ xw,
                                               const float* __restrict__ b2,
                                               const float* __restrict__ b3,
                                               float* __restrict__ z_out,
                                               float* __restrict__ mu_out,
                                               float* __restrict__ lv_out) {
  int n = blockIdx.x;
  int gp = threadIdx.x >> 6;         // wave = pair index
  int lane = threadIdx.x & 63;
  int ulo = 2 * gp, uhi = 2 * gp + 1;
  int off = offs[n], end = offs[n + 1];
  int deg = end - off;
  float adlo = a_d[(size_t)ulo * N_NODES + n];
  float adhi = a_d[(size_t)uhi * N_NODES + n];
  const float* aslo = a_s + (size_t)ulo * N_NODES;
  const float* ashi = a_s + (size_t)uhi * N_NODES;
  const float* xb   = xw + (size_t)gp * N_NODES * 64;
  int g = lane >> 4, q = lane & 15;
  float ax = 0.f, ay = 0.f, az = 0.f, aw = 0.f;

  if (deg <= 64) {
    int s = 0;
    float elo = -1e30f, ehi = -1e30f;
    if (lane < deg) {
      s = ssrc[off + lane];
      elo = lrelu(aslo[s] + adlo);
      ehi = lrelu(ashi[s] + adhi);
    }
    float mlo = elo, mhi = ehi;
#pragma unroll
    for (int o = 32; o > 0; o >>= 1) {
      mlo = fmaxf(mlo, __shfl_xor(mlo, o));
      mhi = fmaxf(mhi, __shfl_xor(mhi, o));
    }
    float plo = (lane < deg) ? __expf(elo - mlo) : 0.f;
    float phi = (lane < deg) ? __expf(ehi - mhi) : 0.f;
    float dlo = plo, dhi = phi;
#pragma unroll
    for (int o = 32; o > 0; o >>= 1) {
      dlo += __shfl_xor(dlo, o);
      dhi += __shfl_xor(dhi, o);
    }
    float allo = plo * (1.f / (dlo + 1e-16f));
    float alhi = phi * (1.f / (dhi + 1e-16f));

    for (int base = 0; base < deg; base += 4) {
      int ee = base + g;
      bool ok = ee < deg;
      int es = ok ? ee : 0;
      float a1 = __shfl(allo, es);
      float a2 = __shfl(alhi, es);
      int   sv = __shfl(s, es);
      if (ok) {
        float al = (q < 8) ? a1 : a2;
        float4 v = *(const float4*)&xb[(size_t)sv * 64 + q * 4];
        ax += al * v.x; ay += al * v.y; az += al * v.z; aw += al * v.w;
      }
    }
  } else {
    float mlo = -1e30f, mhi = -1e30f;
    for (int i = off + lane; i < end; i += 64) {
      int sv = ssrc[i];
      mlo = fmaxf(mlo, lrelu(aslo[sv] + adlo));
      mhi = fmaxf(mhi, lrelu(ashi[sv] + adhi));
    }
#pragma unroll
    for (int o = 32; o > 0; o >>= 1) {
      mlo = fmaxf(mlo, __shfl_xor(mlo, o));
      mhi = fmaxf(mhi, __shfl_xor(mhi, o));
    }
    float dlo = 0.f, dhi = 0.f;
    for (int i = off + lane; i < end; i += 64) {
      int sv = ssrc[i];
      dlo += __expf(lrelu(aslo[sv] + adlo) - mlo);
      dhi += __expf(lrelu(ashi[sv] + adhi) - mhi);
    }
#pragma unroll
    for (int o = 32; o > 0; o >>= 1) {
      dlo += __shfl_xor(dlo, o);
      dhi += __shfl_xor(dhi, o);
    }
    float ilo = 1.f / (dlo + 1e-16f), ihi = 1.f / (dhi + 1e-16f);
    for (int base = off; base < end; base += 4) {
      int e = base + g;
      if (e < end) {
        int sv = ssrc[e];
        float al;
        if (q < 8) al = __expf(lrelu(aslo[sv] + adlo) - mlo) * ilo;
        else       al = __expf(lrelu(ashi[sv] + adhi) - mhi) * ihi;
        float4 v = *(const float4*)&xb[(size_t)sv * 64 + q * 4];
        ax += al * v.x; ay += al * v.y; az += al * v.z; aw += al * v.w;
      }
    }
  }

#pragma unroll
  for (int o = 16; o < 64; o <<= 1) {
    ax += __shfl_xor(ax, o); ay += __shfl_xor(ay, o);
    az += __shfl_xor(az, o); aw += __shfl_xor(aw, o);
  }

  __shared__ float sacc[HEADS][2][32];
  if (g == 0)
    *(float4*)&sacc[gp][q >> 3][(q & 7) * 4] = make_float4(ax, ay, az, aw);
  __syncthreads();
  if (threadIdx.x < 64) {
    int t = threadIdx.x;
    if (t < 32) {
      // layer 2 = units 0..4 = (pair,half): (0,0),(0,1),(1,0),(1,1),(2,0)
      float v = sacc[0][0][t] + sacc[0][1][t] + sacc[1][0][t] + sacc[1][1][t] + sacc[2][0][t];
      v = v * 0.2f + b2[t];
      z_out[(size_t)n * 32 + t]  = v;
      mu_out[(size_t)n * 32 + t] = v;
    } else {
      int c = t - 32;
      // layer 3 = units 5..9 = (2,1),(3,0),(3,1),(4,0),(4,1)
      float v = sacc[2][1][c] + sacc[3][0][c] + sacc[3][1][c] + sacc[4][0][c] + sacc[4][1][c];
      v = v * 0.2f + b3[c];
      lv_out[(size_t)n * 32 + c] = v;
    }
  }
}

// ---------------- launch ----------------
extern "C" void kernel_launch(void* const* d_in, const int* in_sizes, int n_in,
                              void* d_out, int out_size, void* d_ws, size_t ws_size,
                              hipStream_t stream) {
  const float* x        = (const float*)d_in[0];
  const int*   ei       = (const int*)d_in[1];
  const float* W1       = (const float*)d_in[2];
  const float* att_src1 = (const float*)d_in[3];
  const float* att_dst1 = (const float*)d_in[4];
  const float* b1       = (const float*)d_in[5];
  const float* W2       = (const float*)d_in[6];
  const float* att_src2 = (const float*)d_in[7];
  const float* att_dst2 = (const float*)d_in[8];
  const float* b2       = (const float*)d_in[9];
  const float* W3       = (const float*)d_in[10];
  const float* att_src3 = (const float*)d_in[11];
  const float* att_dst3 = (const float*)d_in[12];
  const float* b3       = (const float*)d_in[13];
  float* out = (float*)d_out;

  char* w = (char*)d_ws;
  auto alloc = [&](size_t bytes) -> void* {
    void* p = (void*)w;
    w += (bytes + 255) & ~(size_t)255;
    return p;
  };
  int*   deg    = (int*)alloc((size_t)N_NODES * 4);
  int*   offs   = (int*)alloc((size_t)(N_NODES + 1) * 4);
  int*   cursor = (int*)alloc((size_t)N_NODES * 4);
  int*   bsum   = (int*)alloc((size_t)128 * 4);
  int*   ssrc   = (int*)alloc((size_t)EP * 4);
  float* xw     = (float*)alloc((size_t)N_NODES * 320 * 4);   // 25.6 MB, reused L1 then L2|3
  float* a_s    = (float*)alloc((size_t)N_NODES * 10 * 4);
  float* a_d    = (float*)alloc((size_t)N_NODES * 10 * 4);
  float* h1     = (float*)alloc((size_t)N_NODES * 64 * 4);    // 5.12 MB
  float* Wc     = (float*)alloc((size_t)64 * 320 * 4);
  // total ~33.5 MB

  hipMemsetAsync(deg, 0, (size_t)N_NODES * 4, stream);
  hipMemsetAsync(cursor, 0, (size_t)N_NODES * 4, stream);

  int eb = (EP + 255) / 256;
  int nb = (N_NODES + 255) / 256;   // 79
  count_deg_k<<<eb, 256, 0, stream>>>(ei, deg);
  scan1_k<<<nb, 256, 0, stream>>>(deg, offs, bsum);
  scan2_k<<<1, 128, 0, stream>>>(bsum, nb);
  scan3_k<<<nb, 256, 0, stream>>>(offs, bsum);
  scatter_k<<<eb, 256, 0, stream>>>(ei, offs, cursor, ssrc);
  pack23_k<<<40, 256, 0, stream>>>(W2, W3, Wc);

  dim3 gg(5, 313);   // x = col-tile (fast), y = row-tile: same-A blocks consecutive

  // ---- layer 1 ----
  sgemm_fused_k<64><<<gg, 256, 0, stream>>>(x, W1, xw, att_src1, att_dst1,
                                            nullptr, nullptr, a_s, a_d,
                                            N_NODES, 320, 256);
  agg1_k<<<N_NODES, 320, 0, stream>>>(offs, ssrc, a_s, a_d, xw, b1, h1);

  // ---- layers 2+3 fused ----
  sgemm_fused_k<32><<<gg, 256, 0, stream>>>(h1, Wc, xw, att_src2, att_dst2,
                                            att_src3, att_dst3, a_s, a_d,
                                            N_NODES, 320, 64);
  agg23_k<<<N_NODES, 320, 0, stream>>>(offs, ssrc, a_s, a_d, xw, b2, b3,
                                       out, out + (size_t)N_NODES * 32,
                                       out + (size_t)2 * N_NODES * 32);
}

// Round 9
// 282.734 us; speedup vs baseline: 1.3545x; 1.3545x over previous
//
#include <hip/hip_runtime.h>
#include <math.h>

#define N_NODES 20000
#define N_EDGES 320000
#define EP (N_EDGES + N_NODES)   // with self loops
#define HEADS 5

__device__ __forceinline__ float lrelu(float s) { return (s > 0.f) ? s : 0.2f * s; }

// ---------------- CSR build ----------------
__global__ void count_deg_k(const int* __restrict__ ei, int* __restrict__ deg) {
  int e = blockIdx.x * blockDim.x + threadIdx.x;
  if (e >= EP) return;
  int dst = (e < N_EDGES) ? ei[N_EDGES + e] : (e - N_EDGES);
  atomicAdd(&deg[dst], 1);
}

__global__ __launch_bounds__(256) void scan1_k(const int* __restrict__ deg,
                                               int* __restrict__ offs,
                                               int* __restrict__ bsum) {
  __shared__ int buf[256];
  int tid = threadIdx.x, i = blockIdx.x * 256 + tid;
  int v = (i < N_NODES) ? deg[i] : 0;
  buf[tid] = v;
  __syncthreads();
  for (int o = 1; o < 256; o <<= 1) {
    int t = (tid >= o) ? buf[tid - o] : 0;
    __syncthreads();
    buf[tid] += t;
    __syncthreads();
  }
  if (i < N_NODES) offs[i] = buf[tid] - v;   // block-local exclusive
  if (tid == 255) bsum[blockIdx.x] = buf[255];
}

__global__ __launch_bounds__(128) void scan2_k(int* __restrict__ bsum, int nb) {
  __shared__ int buf[128];
  int tid = threadIdx.x;
  int v = (tid < nb) ? bsum[tid] : 0;
  buf[tid] = v;
  __syncthreads();
  for (int o = 1; o < 128; o <<= 1) {
    int t = (tid >= o) ? buf[tid - o] : 0;
    __syncthreads();
    buf[tid] += t;
    __syncthreads();
  }
  if (tid < nb) bsum[tid] = buf[tid] - v;    // exclusive
}

__global__ void scan3_k(int* __restrict__ offs, const int* __restrict__ bsum) {
  int i = blockIdx.x * 256 + threadIdx.x;
  if (i < N_NODES) offs[i] += bsum[blockIdx.x];
  if (i == 0) offs[N_NODES] = EP;
}

__global__ void scatter_k(const int* __restrict__ ei, const int* __restrict__ offs,
                          int* __restrict__ cursor, int* __restrict__ ssrc) {
  int e = blockIdx.x * blockDim.x + threadIdx.x;
  if (e >= EP) return;
  int src, dst;
  if (e < N_EDGES) { src = ei[e]; dst = ei[N_EDGES + e]; }
  else             { src = e - N_EDGES; dst = src; }
  int pos = atomicAdd(&cursor[dst], 1);
  ssrc[offs[dst] + pos] = src;
}

// ---------------- pack [W2 | W3] into Wc[64][320] ----------------
__global__ void pack23_k(const float* __restrict__ W2, const float* __restrict__ W3,
                         float* __restrict__ Wc) {
  int t = blockIdx.x * blockDim.x + threadIdx.x;   // 64*160
  if (t >= 64 * 160) return;
  int k = t / 160, j = t % 160;
  Wc[k * 320 + j]       = W2[t];
  Wc[k * 320 + 160 + j] = W3[t];
}

// ---------------- fp32 tiled GEMM + fused attention-sums epilogue ----------------
// C[M,N] = A[M,K] @ B[K,N]; BM=BN=64, BK=16, 256 threads, 4x4/thread.
// R7 skeleton (VGPR ~40, 8.7KB LDS, occupancy-friendly) + two fixes:
//   (a) LDS strides padded to 68 (bank-conflict-free: 65 gave 4-way on As stores)
//   (b) register prefetch: issue it+1 loads BEFORE computing it (latency hidden)
// C written in 64-col slices: C[((bn/64)*M + r)*64 + (c-bn)].
// Epilogue: per CH-col unit u (= global_col/CH), as_out[u*M+r] = row . att_s[u].
template <int CH>
__global__ __launch_bounds__(256) void sgemm_fused_k(
    const float* __restrict__ A, const float* __restrict__ B, float* __restrict__ C,
    const float* __restrict__ attAs, const float* __restrict__ attAd,
    const float* __restrict__ attBs, const float* __restrict__ attBd,
    float* __restrict__ as_out, float* __restrict__ ad_out,
    int M, int N, int K) {
  __shared__ float As[16][68];
  __shared__ float Bs[16][68];
  int bm = blockIdx.x * 64, bn = blockIdx.y * 64;
  int tid = threadIdx.x;
  int tr = (tid / 16) * 4;
  int tc = (tid % 16) * 4;
  float acc[4][4] = {};

  int arow = tid >> 2, ac4 = (tid & 3) << 2;     // A tile: 64 rows x 4 float4
  int brow = tid >> 4, bc4 = (tid & 15) << 2;    // B tile: 16 rows x 16 float4

  int nit = K >> 4;
  const float4 zero4 = make_float4(0.f, 0.f, 0.f, 0.f);

  // prologue: tile 0 regs -> LDS
  float4 pa = (bm + arow < M) ? *(const float4*)&A[(size_t)(bm + arow) * K + ac4] : zero4;
  float4 pb = *(const float4*)&B[(size_t)brow * N + bn + bc4];
  As[ac4 + 0][arow] = pa.x; As[ac4 + 1][arow] = pa.y;
  As[ac4 + 2][arow] = pa.z; As[ac4 + 3][arow] = pa.w;
  *(float4*)&Bs[brow][bc4] = pb;
  __syncthreads();

  for (int it = 0; it < nit; ++it) {
    bool more = (it + 1 < nit);
    if (more) {                       // issue next-tile loads BEFORE compute
      int k0 = (it + 1) << 4;
      pa = (bm + arow < M) ? *(const float4*)&A[(size_t)(bm + arow) * K + k0 + ac4] : zero4;
      pb = *(const float4*)&B[(size_t)(k0 + brow) * N + bn + bc4];
    }
#pragma unroll
    for (int k = 0; k < 16; k++) {
      float av[4], bv[4];
#pragma unroll
      for (int j = 0; j < 4; j++) { av[j] = As[k][tr + j]; bv[j] = Bs[k][tc + j]; }
#pragma unroll
      for (int i = 0; i < 4; i++)
#pragma unroll
        for (int j = 0; j < 4; j++) acc[i][j] += av[i] * bv[j];
    }
    if (more) {
      __syncthreads();
      As[ac4 + 0][arow] = pa.x; As[ac4 + 1][arow] = pa.y;
      As[ac4 + 2][arow] = pa.z; As[ac4 + 3][arow] = pa.w;
      *(float4*)&Bs[brow][bc4] = pb;
      __syncthreads();
    }
  }

  int gs = bn >> 6;
#pragma unroll
  for (int i = 0; i < 4; i++) {
    int r = bm + tr + i;
    if (r < M)
      *(float4*)&C[((size_t)gs * M + r) * 64 + tc] =
          make_float4(acc[i][0], acc[i][1], acc[i][2], acc[i][3]);
  }

  // fused attention sums
  int u  = (bn + tc) / CH;
  int cc = tc % CH;
  const float* avs; const float* avd;
  if (CH == 64)       { avs = attAs + u * 64 + cc;           avd = attAd + u * 64 + cc; }
  else if (u < HEADS) { avs = attAs + u * 32 + cc;           avd = attAd + u * 32 + cc; }
  else                { avs = attBs + (u - HEADS) * 32 + cc; avd = attBd + (u - HEADS) * 32 + cc; }
  float w_s[4], w_d[4];
#pragma unroll
  for (int j = 0; j < 4; j++) { w_s[j] = avs[j]; w_d[j] = avd[j]; }
#pragma unroll
  for (int i = 0; i < 4; i++) {
    float ps = acc[i][0] * w_s[0] + acc[i][1] * w_s[1] + acc[i][2] * w_s[2] + acc[i][3] * w_s[3];
    float pd = acc[i][0] * w_d[0] + acc[i][1] * w_d[1] + acc[i][2] * w_d[2] + acc[i][3] * w_d[3];
#pragma unroll
    for (int o = 1; o < CH / 4; o <<= 1) {
      ps += __shfl_xor(ps, o);
      pd += __shfl_xor(pd, o);
    }
    int r = bm + tr + i;
    if (((tid & ((CH / 4) - 1)) == 0) && r < M) {
      as_out[(size_t)u * M + r] = ps;
      ad_out[(size_t)u * M + r] = pd;
    }
  }
}

// ---------------- layer 1: block per node, 5 waves (wave = head), LDS reduce ----------------
// __shfl broadcasts stay OUTSIDE divergent guards (ds_bpermute from inactive lane
// is undefined on CDNA — was the R3-R5 bug).
__global__ __launch_bounds__(320) void agg1_k(const int* __restrict__ offs,
                                              const int* __restrict__ ssrc,
                                              const float* __restrict__ a_s,
                                              const float* __restrict__ a_d,
                                              const float* __restrict__ xw,
                                              const float* __restrict__ b1,
                                              float* __restrict__ h1) {
  int n = blockIdx.x;
  int u = threadIdx.x >> 6;          // wave = head/unit
  int lane = threadIdx.x & 63;
  int off = offs[n], end = offs[n + 1];
  int deg = end - off;
  float ad = a_d[(size_t)u * N_NODES + n];
  const float* asl = a_s + (size_t)u * N_NODES;
  const float* xb  = xw + (size_t)u * N_NODES * 64;
  int g = lane >> 4, q = lane & 15;
  float ax = 0.f, ay = 0.f, az = 0.f, aw = 0.f;

  if (deg <= 64) {
    int s = 0;
    float e = -1e30f;
    if (lane < deg) { s = ssrc[off + lane]; e = lrelu(asl[s] + ad); }
    float m = e;
#pragma unroll
    for (int o = 32; o > 0; o >>= 1) m = fmaxf(m, __shfl_xor(m, o));
    float p = (lane < deg) ? __expf(e - m) : 0.f;
    float den = p;
#pragma unroll
    for (int o = 32; o > 0; o >>= 1) den += __shfl_xor(den, o);
    float alpha = p * (1.f / (den + 1e-16f));

    for (int base = 0; base < deg; base += 4) {
      int ee = base + g;
      bool ok = ee < deg;
      int es = ok ? ee : 0;             // clamp: all lanes + sources active
      float al = __shfl(alpha, es);
      int   sv = __shfl(s, es);
      if (ok) {
        float4 v = *(const float4*)&xb[(size_t)sv * 64 + q * 4];
        ax += al * v.x; ay += al * v.y; az += al * v.z; aw += al * v.w;
      }
    }
  } else {
    float m = -1e30f;
    for (int i = off + lane; i < end; i += 64) m = fmaxf(m, lrelu(asl[ssrc[i]] + ad));
#pragma unroll
    for (int o = 32; o > 0; o >>= 1) m = fmaxf(m, __shfl_xor(m, o));
    float den = 0.f;
    for (int i = off + lane; i < end; i += 64) den += __expf(lrelu(asl[ssrc[i]] + ad) - m);
#pragma unroll
    for (int o = 32; o > 0; o >>= 1) den += __shfl_xor(den, o);
    float inv = 1.f / (den + 1e-16f);
    for (int base = off; base < end; base += 4) {
      int e = base + g;
      if (e < end) {
        int sv = ssrc[e];
        float al = __expf(lrelu(asl[sv] + ad) - m) * inv;
        float4 v = *(const float4*)&xb[(size_t)sv * 64 + q * 4];
        ax += al * v.x; ay += al * v.y; az += al * v.z; aw += al * v.w;
      }
    }
  }

#pragma unroll
  for (int o = 16; o < 64; o <<= 1) {
    ax += __shfl_xor(ax, o); ay += __shfl_xor(ay, o);
    az += __shfl_xor(az, o); aw += __shfl_xor(aw, o);
  }

  __shared__ float sacc[HEADS][64];
  if (g == 0) *(float4*)&sacc[u][q * 4] = make_float4(ax, ay, az, aw);
  __syncthreads();
  if (threadIdx.x < 64) {
    int t = threadIdx.x;
    float v = sacc[0][t] + sacc[1][t] + sacc[2][t] + sacc[3][t] + sacc[4][t];
    v = v * 0.2f + b1[t];
    h1[(size_t)n * 64 + t] = fmaxf(v, 0.f);
  }
}

// ---------------- layers 2+3: block per node, 5 waves (wave = pair 2g,2g+1) ----------------
// slice g: cols 0-31 = unit 2g, cols 32-63 = unit 2g+1. Units 0-4 -> layer2, 5-9 -> layer3.
__global__ __launch_bounds__(320) void agg23_k(const int* __restrict__ offs,
                                               const int* __restrict__ ssrc,
                                               const float* __restrict__ a_s,
                                               const float* __restrict__ a_d,
                                               const float* __restrict__ xw,
                                               const float* __restrict__ b2,
                                               const float* __restrict__ b3,
                                               float* __restrict__ z_out,
                                               float* __restrict__ mu_out,
                                               float* __restrict__ lv_out) {
  int n = blockIdx.x;
  int gp = threadIdx.x >> 6;         // wave = pair index
  int lane = threadIdx.x & 63;
  int ulo = 2 * gp, uhi = 2 * gp + 1;
  int off = offs[n], end = offs[n + 1];
  int deg = end - off;
  float adlo = a_d[(size_t)ulo * N_NODES + n];
  float adhi = a_d[(size_t)uhi * N_NODES + n];
  const float* aslo = a_s + (size_t)ulo * N_NODES;
  const float* ashi = a_s + (size_t)uhi * N_NODES;
  const float* xb   = xw + (size_t)gp * N_NODES * 64;
  int g = lane >> 4, q = lane & 15;
  float ax = 0.f, ay = 0.f, az = 0.f, aw = 0.f;

  if (deg <= 64) {
    int s = 0;
    float elo = -1e30f, ehi = -1e30f;
    if (lane < deg) {
      s = ssrc[off + lane];
      elo = lrelu(aslo[s] + adlo);
      ehi = lrelu(ashi[s] + adhi);
    }
    float mlo = elo, mhi = ehi;
#pragma unroll
    for (int o = 32; o > 0; o >>= 1) {
      mlo = fmaxf(mlo, __shfl_xor(mlo, o));
      mhi = fmaxf(mhi, __shfl_xor(mhi, o));
    }
    float plo = (lane < deg) ? __expf(elo - mlo) : 0.f;
    float phi = (lane < deg) ? __expf(ehi - mhi) : 0.f;
    float dlo = plo, dhi = phi;
#pragma unroll
    for (int o = 32; o > 0; o >>= 1) {
      dlo += __shfl_xor(dlo, o);
      dhi += __shfl_xor(dhi, o);
    }
    float allo = plo * (1.f / (dlo + 1e-16f));
    float alhi = phi * (1.f / (dhi + 1e-16f));

    for (int base = 0; base < deg; base += 4) {
      int ee = base + g;
      bool ok = ee < deg;
      int es = ok ? ee : 0;
      float a1 = __shfl(allo, es);
      float a2 = __shfl(alhi, es);
      int   sv = __shfl(s, es);
      if (ok) {
        float al = (q < 8) ? a1 : a2;
        float4 v = *(const float4*)&xb[(size_t)sv * 64 + q * 4];
        ax += al * v.x; ay += al * v.y; az += al * v.z; aw += al * v.w;
      }
    }
  } else {
    float mlo = -1e30f, mhi = -1e30f;
    for (int i = off + lane; i < end; i += 64) {
      int sv = ssrc[i];
      mlo = fmaxf(mlo, lrelu(aslo[sv] + adlo));
      mhi = fmaxf(mhi, lrelu(ashi[sv] + adhi));
    }
#pragma unroll
    for (int o = 32; o > 0; o >>= 1) {
      mlo = fmaxf(mlo, __shfl_xor(mlo, o));
      mhi = fmaxf(mhi, __shfl_xor(mhi, o));
    }
    float dlo = 0.f, dhi = 0.f;
    for (int i = off + lane; i < end; i += 64) {
      int sv = ssrc[i];
      dlo += __expf(lrelu(aslo[sv] + adlo) - mlo);
      dhi += __expf(lrelu(ashi[sv] + adhi) - mhi);
    }
#pragma unroll
    for (int o = 32; o > 0; o >>= 1) {
      dlo += __shfl_xor(dlo, o);
      dhi += __shfl_xor(dhi, o);
    }
    float ilo = 1.f / (dlo + 1e-16f), ihi = 1.f / (dhi + 1e-16f);
    for (int base = off; base < end; base += 4) {
      int e = base + g;
      if (e < end) {
        int sv = ssrc[e];
        float al;
        if (q < 8) al = __expf(lrelu(aslo[sv] + adlo) - mlo) * ilo;
        else       al = __expf(lrelu(ashi[sv] + adhi) - mhi) * ihi;
        float4 v = *(const float4*)&xb[(size_t)sv * 64 + q * 4];
        ax += al * v.x; ay += al * v.y; az += al * v.z; aw += al * v.w;
      }
    }
  }

#pragma unroll
  for (int o = 16; o < 64; o <<= 1) {
    ax += __shfl_xor(ax, o); ay += __shfl_xor(ay, o);
    az += __shfl_xor(az, o); aw += __shfl_xor(aw, o);
  }

  __shared__ float sacc[HEADS][2][32];
  if (g == 0)
    *(float4*)&sacc[gp][q >> 3][(q & 7) * 4] = make_float4(ax, ay, az, aw);
  __syncthreads();
  if (threadIdx.x < 64) {
    int t = threadIdx.x;
    if (t < 32) {
      // layer 2 = units 0..4 = (pair,half): (0,0),(0,1),(1,0),(1,1),(2,0)
      float v = sacc[0][0][t] + sacc[0][1][t] + sacc[1][0][t] + sacc[1][1][t] + sacc[2][0][t];
      v = v * 0.2f + b2[t];
      z_out[(size_t)n * 32 + t]  = v;
      mu_out[(size_t)n * 32 + t] = v;
    } else {
      int c = t - 32;
      // layer 3 = units 5..9 = (2,1),(3,0),(3,1),(4,0),(4,1)
      float v = sacc[2][1][c] + sacc[3][0][c] + sacc[3][1][c] + sacc[4][0][c] + sacc[4][1][c];
      v = v * 0.2f + b3[c];
      lv_out[(size_t)n * 32 + c] = v;
    }
  }
}

// ---------------- launch ----------------
extern "C" void kernel_launch(void* const* d_in, const int* in_sizes, int n_in,
                              void* d_out, int out_size, void* d_ws, size_t ws_size,
                              hipStream_t stream) {
  const float* x        = (const float*)d_in[0];
  const int*   ei       = (const int*)d_in[1];
  const float* W1       = (const float*)d_in[2];
  const float* att_src1 = (const float*)d_in[3];
  const float* att_dst1 = (const float*)d_in[4];
  const float* b1       = (const float*)d_in[5];
  const float* W2       = (const float*)d_in[6];
  const float* att_src2 = (const float*)d_in[7];
  const float* att_dst2 = (const float*)d_in[8];
  const float* b2       = (const float*)d_in[9];
  const float* W3       = (const float*)d_in[10];
  const float* att_src3 = (const float*)d_in[11];
  const float* att_dst3 = (const float*)d_in[12];
  const float* b3       = (const float*)d_in[13];
  float* out = (float*)d_out;

  char* w = (char*)d_ws;
  auto alloc = [&](size_t bytes) -> void* {
    void* p = (void*)w;
    w += (bytes + 255) & ~(size_t)255;
    return p;
  };
  int*   deg    = (int*)alloc((size_t)N_NODES * 4);
  int*   offs   = (int*)alloc((size_t)(N_NODES + 1) * 4);
  int*   cursor = (int*)alloc((size_t)N_NODES * 4);
  int*   bsum   = (int*)alloc((size_t)128 * 4);
  int*   ssrc   = (int*)alloc((size_t)EP * 4);
  float* xw     = (float*)alloc((size_t)N_NODES * 320 * 4);   // 25.6 MB, reused L1 then L2|3
  float* a_s    = (float*)alloc((size_t)N_NODES * 10 * 4);
  float* a_d    = (float*)alloc((size_t)N_NODES * 10 * 4);
  float* h1     = (float*)alloc((size_t)N_NODES * 64 * 4);    // 5.12 MB
  float* Wc     = (float*)alloc((size_t)64 * 320 * 4);
  // total ~33.5 MB

  hipMemsetAsync(deg, 0, (size_t)N_NODES * 4, stream);
  hipMemsetAsync(cursor, 0, (size_t)N_NODES * 4, stream);

  int eb = (EP + 255) / 256;
  int nb = (N_NODES + 255) / 256;   // 79
  count_deg_k<<<eb, 256, 0, stream>>>(ei, deg);
  scan1_k<<<nb, 256, 0, stream>>>(deg, offs, bsum);
  scan2_k<<<1, 128, 0, stream>>>(bsum, nb);
  scan3_k<<<nb, 256, 0, stream>>>(offs, bsum);
  scatter_k<<<eb, 256, 0, stream>>>(ei, offs, cursor, ssrc);
  pack23_k<<<40, 256, 0, stream>>>(W2, W3, Wc);

  dim3 gg(313, 5);

  // ---- layer 1 ----
  sgemm_fused_k<64><<<gg, 256, 0, stream>>>(x, W1, xw, att_src1, att_dst1,
                                            nullptr, nullptr, a_s, a_d,
                                            N_NODES, 320, 256);
  agg1_k<<<N_NODES, 320, 0, stream>>>(offs, ssrc, a_s, a_d, xw, b1, h1);

  // ---- layers 2+3 fused ----
  sgemm_fused_k<32><<<gg, 256, 0, stream>>>(h1, Wc, xw, att_src2, att_dst2,
                                            att_src3, att_dst3, a_s, a_d,
                                            N_NODES, 320, 64);
  agg23_k<<<N_NODES, 320, 0, stream>>>(offs, ssrc, a_s, a_d, xw, b2, b3,
                                       out, out + (size_t)N_NODES * 32,
                                       out + (size_t)2 * N_NODES * 32);
}

// Round 10
// 265.318 us; speedup vs baseline: 1.4434x; 1.0656x over previous
//
#include <hip/hip_runtime.h>
#include <math.h>

#define N_NODES 20000
#define N_EDGES 320000
#define EP (N_EDGES + N_NODES)   // with self loops
#define HEADS 5

__device__ __forceinline__ float lrelu(float s) { return (s > 0.f) ? s : 0.2f * s; }

// ---------------- CSR build ----------------
__global__ void count_deg_k(const int* __restrict__ ei, int* __restrict__ deg) {
  int e = blockIdx.x * blockDim.x + threadIdx.x;
  if (e >= EP) return;
  int dst = (e < N_EDGES) ? ei[N_EDGES + e] : (e - N_EDGES);
  atomicAdd(&deg[dst], 1);
}

__global__ __launch_bounds__(256) void scan1_k(const int* __restrict__ deg,
                                               int* __restrict__ offs,
                                               int* __restrict__ bsum) {
  __shared__ int buf[256];
  int tid = threadIdx.x, i = blockIdx.x * 256 + tid;
  int v = (i < N_NODES) ? deg[i] : 0;
  buf[tid] = v;
  __syncthreads();
  for (int o = 1; o < 256; o <<= 1) {
    int t = (tid >= o) ? buf[tid - o] : 0;
    __syncthreads();
    buf[tid] += t;
    __syncthreads();
  }
  if (i < N_NODES) offs[i] = buf[tid] - v;   // block-local exclusive
  if (tid == 255) bsum[blockIdx.x] = buf[255];
}

__global__ __launch_bounds__(128) void scan2_k(int* __restrict__ bsum, int nb) {
  __shared__ int buf[128];
  int tid = threadIdx.x;
  int v = (tid < nb) ? bsum[tid] : 0;
  buf[tid] = v;
  __syncthreads();
  for (int o = 1; o < 128; o <<= 1) {
    int t = (tid >= o) ? buf[tid - o] : 0;
    __syncthreads();
    buf[tid] += t;
    __syncthreads();
  }
  if (tid < nb) bsum[tid] = buf[tid] - v;    // exclusive
}

__global__ void scan3_k(int* __restrict__ offs, const int* __restrict__ bsum) {
  int i = blockIdx.x * 256 + threadIdx.x;
  if (i < N_NODES) offs[i] += bsum[blockIdx.x];
  if (i == 0) offs[N_NODES] = EP;
}

__global__ void scatter_k(const int* __restrict__ ei, const int* __restrict__ offs,
                          int* __restrict__ cursor, int* __restrict__ ssrc) {
  int e = blockIdx.x * blockDim.x + threadIdx.x;
  if (e >= EP) return;
  int src, dst;
  if (e < N_EDGES) { src = ei[e]; dst = ei[N_EDGES + e]; }
  else             { src = e - N_EDGES; dst = src; }
  int pos = atomicAdd(&cursor[dst], 1);
  ssrc[offs[dst] + pos] = src;
}

// ---------------- pack [W2 | W3] into Wc[64][320] ----------------
__global__ void pack23_k(const float* __restrict__ W2, const float* __restrict__ W3,
                         float* __restrict__ Wc) {
  int t = blockIdx.x * blockDim.x + threadIdx.x;   // 64*160
  if (t >= 64 * 160) return;
  int k = t / 160, j = t % 160;
  Wc[k * 320 + j]       = W2[t];
  Wc[k * 320 + 160 + j] = W3[t];
}

// ---------------- fp32 tiled GEMM + fused attention-sums epilogue ----------------
// C[M,N] = A[M,K] @ B[K,N]; BM=BN=64, BK=16, 256 threads, 4x4/thread.
// LDS stride 68 (conflict-free), single buffer, register prefetch (loads for
// it+1 issued before computing it). C written in 64-col slices.
template <int CH>
__global__ __launch_bounds__(256) void sgemm_fused_k(
    const float* __restrict__ A, const float* __restrict__ B, float* __restrict__ C,
    const float* __restrict__ attAs, const float* __restrict__ attAd,
    const float* __restrict__ attBs, const float* __restrict__ attBd,
    float* __restrict__ as_out, float* __restrict__ ad_out,
    int M, int N, int K) {
  __shared__ float As[16][68];
  __shared__ float Bs[16][68];
  int bm = blockIdx.x * 64, bn = blockIdx.y * 64;
  int tid = threadIdx.x;
  int tr = (tid / 16) * 4;
  int tc = (tid % 16) * 4;
  float acc[4][4] = {};

  int arow = tid >> 2, ac4 = (tid & 3) << 2;     // A tile: 64 rows x 4 float4
  int brow = tid >> 4, bc4 = (tid & 15) << 2;    // B tile: 16 rows x 16 float4

  int nit = K >> 4;
  const float4 zero4 = make_float4(0.f, 0.f, 0.f, 0.f);

  float4 pa = (bm + arow < M) ? *(const float4*)&A[(size_t)(bm + arow) * K + ac4] : zero4;
  float4 pb = *(const float4*)&B[(size_t)brow * N + bn + bc4];
  As[ac4 + 0][arow] = pa.x; As[ac4 + 1][arow] = pa.y;
  As[ac4 + 2][arow] = pa.z; As[ac4 + 3][arow] = pa.w;
  *(float4*)&Bs[brow][bc4] = pb;
  __syncthreads();

  for (int it = 0; it < nit; ++it) {
    bool more = (it + 1 < nit);
    if (more) {
      int k0 = (it + 1) << 4;
      pa = (bm + arow < M) ? *(const float4*)&A[(size_t)(bm + arow) * K + k0 + ac4] : zero4;
      pb = *(const float4*)&B[(size_t)(k0 + brow) * N + bn + bc4];
    }
#pragma unroll
    for (int k = 0; k < 16; k++) {
      float av[4], bv[4];
#pragma unroll
      for (int j = 0; j < 4; j++) { av[j] = As[k][tr + j]; bv[j] = Bs[k][tc + j]; }
#pragma unroll
      for (int i = 0; i < 4; i++)
#pragma unroll
        for (int j = 0; j < 4; j++) acc[i][j] += av[i] * bv[j];
    }
    if (more) {
      __syncthreads();
      As[ac4 + 0][arow] = pa.x; As[ac4 + 1][arow] = pa.y;
      As[ac4 + 2][arow] = pa.z; As[ac4 + 3][arow] = pa.w;
      *(float4*)&Bs[brow][bc4] = pb;
      __syncthreads();
    }
  }

  int gs = bn >> 6;
#pragma unroll
  for (int i = 0; i < 4; i++) {
    int r = bm + tr + i;
    if (r < M)
      *(float4*)&C[((size_t)gs * M + r) * 64 + tc] =
          make_float4(acc[i][0], acc[i][1], acc[i][2], acc[i][3]);
  }

  // fused attention sums
  int u  = (bn + tc) / CH;
  int cc = tc % CH;
  const float* avs; const float* avd;
  if (CH == 64)       { avs = attAs + u * 64 + cc;           avd = attAd + u * 64 + cc; }
  else if (u < HEADS) { avs = attAs + u * 32 + cc;           avd = attAd + u * 32 + cc; }
  else                { avs = attBs + (u - HEADS) * 32 + cc; avd = attBd + (u - HEADS) * 32 + cc; }
  float w_s[4], w_d[4];
#pragma unroll
  for (int j = 0; j < 4; j++) { w_s[j] = avs[j]; w_d[j] = avd[j]; }
#pragma unroll
  for (int i = 0; i < 4; i++) {
    float ps = acc[i][0] * w_s[0] + acc[i][1] * w_s[1] + acc[i][2] * w_s[2] + acc[i][3] * w_s[3];
    float pd = acc[i][0] * w_d[0] + acc[i][1] * w_d[1] + acc[i][2] * w_d[2] + acc[i][3] * w_d[3];
#pragma unroll
    for (int o = 1; o < CH / 4; o <<= 1) {
      ps += __shfl_xor(ps, o);
      pd += __shfl_xor(pd, o);
    }
    int r = bm + tr + i;
    if (((tid & ((CH / 4) - 1)) == 0) && r < M) {
      as_out[(size_t)u * M + r] = ps;
      ad_out[(size_t)u * M + r] = pd;
    }
  }
}

// ---------------- layer 1: block per node, 5 waves (wave = head), LDS reduce ----------------
// Fast-path gather: 16 edges in flight (4x unroll), fully convergent — shuffle
// source clamped to edge 0 (self-loop guarantees validity), alpha zeroed for
// tail lanes, loads unconditional (same-address tail loads coalesce ~free).
// __shfl executed by ALL lanes (ds_bpermute from inactive lane undefined on CDNA).
__global__ __launch_bounds__(320) void agg1_k(const int* __restrict__ offs,
                                              const int* __restrict__ ssrc,
                                              const float* __restrict__ a_s,
                                              const float* __restrict__ a_d,
                                              const float* __restrict__ xw,
                                              const float* __restrict__ b1,
                                              float* __restrict__ h1) {
  int n = blockIdx.x;
  int u = threadIdx.x >> 6;          // wave = head/unit
  int lane = threadIdx.x & 63;
  int off = offs[n], end = offs[n + 1];
  int deg = end - off;
  float ad = a_d[(size_t)u * N_NODES + n];
  const float* asl = a_s + (size_t)u * N_NODES;
  const float* xb  = xw + (size_t)u * N_NODES * 64;
  int g = lane >> 4, q = lane & 15;
  float ax = 0.f, ay = 0.f, az = 0.f, aw = 0.f;

  if (deg <= 64) {
    int s = 0;
    float e = -1e30f;
    if (lane < deg) { s = ssrc[off + lane]; e = lrelu(asl[s] + ad); }
    float m = e;
#pragma unroll
    for (int o = 32; o > 0; o >>= 1) m = fmaxf(m, __shfl_xor(m, o));
    float p = (lane < deg) ? __expf(e - m) : 0.f;
    float den = p;
#pragma unroll
    for (int o = 32; o > 0; o >>= 1) den += __shfl_xor(den, o);
    float alpha = p * (1.f / (den + 1e-16f));

    for (int base = 0; base < deg; base += 16) {
      float alv[4];
      float4 v[4];
#pragma unroll
      for (int t = 0; t < 4; t++) {
        int ee = base + t * 4 + g;
        bool ok = ee < deg;
        int es = ok ? ee : 0;                 // lane 0 always valid (self-loop)
        float alr = __shfl(alpha, es);        // all 64 lanes execute
        int   sv  = __shfl(s, es);
        alv[t] = ok ? alr : 0.f;
        v[t] = *(const float4*)&xb[(size_t)sv * 64 + q * 4];   // unconditional
      }
#pragma unroll
      for (int t = 0; t < 4; t++) {
        ax += alv[t] * v[t].x; ay += alv[t] * v[t].y;
        az += alv[t] * v[t].z; aw += alv[t] * v[t].w;
      }
    }
  } else {
    float m = -1e30f;
    for (int i = off + lane; i < end; i += 64) m = fmaxf(m, lrelu(asl[ssrc[i]] + ad));
#pragma unroll
    for (int o = 32; o > 0; o >>= 1) m = fmaxf(m, __shfl_xor(m, o));
    float den = 0.f;
    for (int i = off + lane; i < end; i += 64) den += __expf(lrelu(asl[ssrc[i]] + ad) - m);
#pragma unroll
    for (int o = 32; o > 0; o >>= 1) den += __shfl_xor(den, o);
    float inv = 1.f / (den + 1e-16f);
    for (int base = off; base < end; base += 4) {
      int e = base + g;
      if (e < end) {
        int sv = ssrc[e];
        float al = __expf(lrelu(asl[sv] + ad) - m) * inv;
        float4 v = *(const float4*)&xb[(size_t)sv * 64 + q * 4];
        ax += al * v.x; ay += al * v.y; az += al * v.z; aw += al * v.w;
      }
    }
  }

#pragma unroll
  for (int o = 16; o < 64; o <<= 1) {
    ax += __shfl_xor(ax, o); ay += __shfl_xor(ay, o);
    az += __shfl_xor(az, o); aw += __shfl_xor(aw, o);
  }

  __shared__ float sacc[HEADS][64];
  if (g == 0) *(float4*)&sacc[u][q * 4] = make_float4(ax, ay, az, aw);
  __syncthreads();
  if (threadIdx.x < 64) {
    int t = threadIdx.x;
    float v = sacc[0][t] + sacc[1][t] + sacc[2][t] + sacc[3][t] + sacc[4][t];
    v = v * 0.2f + b1[t];
    h1[(size_t)n * 64 + t] = fmaxf(v, 0.f);
  }
}

// ---------------- layers 2+3: block per node, 5 waves (wave = pair 2g,2g+1) ----------------
__global__ __launch_bounds__(320) void agg23_k(const int* __restrict__ offs,
                                               const int* __restrict__ ssrc,
                                               const float* __restrict__ a_s,
                                               const float* __restrict__ a_d,
                                               const float* __restrict__ xw,
                                               const float* __restrict__ b2,
                                               const float* __restrict__ b3,
                                               float* __restrict__ z_out,
                                               float* __restrict__ mu_out,
                                               float* __restrict__ lv_out) {
  int n = blockIdx.x;
  int gp = threadIdx.x >> 6;         // wave = pair index
  int lane = threadIdx.x & 63;
  int ulo = 2 * gp, uhi = 2 * gp + 1;
  int off = offs[n], end = offs[n + 1];
  int deg = end - off;
  float adlo = a_d[(size_t)ulo * N_NODES + n];
  float adhi = a_d[(size_t)uhi * N_NODES + n];
  const float* aslo = a_s + (size_t)ulo * N_NODES;
  const float* ashi = a_s + (size_t)uhi * N_NODES;
  const float* xb   = xw + (size_t)gp * N_NODES * 64;
  int g = lane >> 4, q = lane & 15;
  float ax = 0.f, ay = 0.f, az = 0.f, aw = 0.f;

  if (deg <= 64) {
    int s = 0;
    float elo = -1e30f, ehi = -1e30f;
    if (lane < deg) {
      s = ssrc[off + lane];
      elo = lrelu(aslo[s] + adlo);
      ehi = lrelu(ashi[s] + adhi);
    }
    float mlo = elo, mhi = ehi;
#pragma unroll
    for (int o = 32; o > 0; o >>= 1) {
      mlo = fmaxf(mlo, __shfl_xor(mlo, o));
      mhi = fmaxf(mhi, __shfl_xor(mhi, o));
    }
    float plo = (lane < deg) ? __expf(elo - mlo) : 0.f;
    float phi = (lane < deg) ? __expf(ehi - mhi) : 0.f;
    float dlo = plo, dhi = phi;
#pragma unroll
    for (int o = 32; o > 0; o >>= 1) {
      dlo += __shfl_xor(dlo, o);
      dhi += __shfl_xor(dhi, o);
    }
    float allo = plo * (1.f / (dlo + 1e-16f));
    float alhi = phi * (1.f / (dhi + 1e-16f));

    for (int base = 0; base < deg; base += 16) {
      float alv[4];
      float4 v[4];
#pragma unroll
      for (int t = 0; t < 4; t++) {
        int ee = base + t * 4 + g;
        bool ok = ee < deg;
        int es = ok ? ee : 0;                 // lane 0 always valid
        float a1 = __shfl(allo, es);          // all 64 lanes execute
        float a2 = __shfl(alhi, es);
        int   sv = __shfl(s, es);
        float alr = (q < 8) ? a1 : a2;
        alv[t] = ok ? alr : 0.f;
        v[t] = *(const float4*)&xb[(size_t)sv * 64 + q * 4];   // unconditional
      }
#pragma unroll
      for (int t = 0; t < 4; t++) {
        ax += alv[t] * v[t].x; ay += alv[t] * v[t].y;
        az += alv[t] * v[t].z; aw += alv[t] * v[t].w;
      }
    }
  } else {
    float mlo = -1e30f, mhi = -1e30f;
    for (int i = off + lane; i < end; i += 64) {
      int sv = ssrc[i];
      mlo = fmaxf(mlo, lrelu(aslo[sv] + adlo));
      mhi = fmaxf(mhi, lrelu(ashi[sv] + adhi));
    }
#pragma unroll
    for (int o = 32; o > 0; o >>= 1) {
      mlo = fmaxf(mlo, __shfl_xor(mlo, o));
      mhi = fmaxf(mhi, __shfl_xor(mhi, o));
    }
    float dlo = 0.f, dhi = 0.f;
    for (int i = off + lane; i < end; i += 64) {
      int sv = ssrc[i];
      dlo += __expf(lrelu(aslo[sv] + adlo) - mlo);
      dhi += __expf(lrelu(ashi[sv] + adhi) - mhi);
    }
#pragma unroll
    for (int o = 32; o > 0; o >>= 1) {
      dlo += __shfl_xor(dlo, o);
      dhi += __shfl_xor(dhi, o);
    }
    float ilo = 1.f / (dlo + 1e-16f), ihi = 1.f / (dhi + 1e-16f);
    for (int base = off; base < end; base += 4) {
      int e = base + g;
      if (e < end) {
        int sv = ssrc[e];
        float al;
        if (q < 8) al = __expf(lrelu(aslo[sv] + adlo) - mlo) * ilo;
        else       al = __expf(lrelu(ashi[sv] + adhi) - mhi) * ihi;
        float4 v = *(const float4*)&xb[(size_t)sv * 64 + q * 4];
        ax += al * v.x; ay += al * v.y; az += al * v.z; aw += al * v.w;
      }
    }
  }

#pragma unroll
  for (int o = 16; o < 64; o <<= 1) {
    ax += __shfl_xor(ax, o); ay += __shfl_xor(ay, o);
    az += __shfl_xor(az, o); aw += __shfl_xor(aw, o);
  }

  __shared__ float sacc[HEADS][2][32];
  if (g == 0)
    *(float4*)&sacc[gp][q >> 3][(q & 7) * 4] = make_float4(ax, ay, az, aw);
  __syncthreads();
  if (threadIdx.x < 64) {
    int t = threadIdx.x;
    if (t < 32) {
      float v = sacc[0][0][t] + sacc[0][1][t] + sacc[1][0][t] + sacc[1][1][t] + sacc[2][0][t];
      v = v * 0.2f + b2[t];
      z_out[(size_t)n * 32 + t]  = v;
      mu_out[(size_t)n * 32 + t] = v;
    } else {
      int c = t - 32;
      float v = sacc[2][1][c] + sacc[3][0][c] + sacc[3][1][c] + sacc[4][0][c] + sacc[4][1][c];
      v = v * 0.2f + b3[c];
      lv_out[(size_t)n * 32 + c] = v;
    }
  }
}

// ---------------- launch ----------------
extern "C" void kernel_launch(void* const* d_in, const int* in_sizes, int n_in,
                              void* d_out, int out_size, void* d_ws, size_t ws_size,
                              hipStream_t stream) {
  const float* x        = (const float*)d_in[0];
  const int*   ei       = (const int*)d_in[1];
  const float* W1       = (const float*)d_in[2];
  const float* att_src1 = (const float*)d_in[3];
  const float* att_dst1 = (const float*)d_in[4];
  const float* b1       = (const float*)d_in[5];
  const float* W2       = (const float*)d_in[6];
  const float* att_src2 = (const float*)d_in[7];
  const float* att_dst2 = (const float*)d_in[8];
  const float* b2       = (const float*)d_in[9];
  const float* W3       = (const float*)d_in[10];
  const float* att_src3 = (const float*)d_in[11];
  const float* att_dst3 = (const float*)d_in[12];
  const float* b3       = (const float*)d_in[13];
  float* out = (float*)d_out;

  char* w = (char*)d_ws;
  auto alloc = [&](size_t bytes) -> void* {
    void* p = (void*)w;
    w += (bytes + 255) & ~(size_t)255;
    return p;
  };
  int*   deg    = (int*)alloc((size_t)N_NODES * 4);
  int*   offs   = (int*)alloc((size_t)(N_NODES + 1) * 4);
  int*   cursor = (int*)alloc((size_t)N_NODES * 4);
  int*   bsum   = (int*)alloc((size_t)128 * 4);
  int*   ssrc   = (int*)alloc((size_t)EP * 4);
  float* xw     = (float*)alloc((size_t)N_NODES * 320 * 4);   // 25.6 MB, reused L1 then L2|3
  float* a_s    = (float*)alloc((size_t)N_NODES * 10 * 4);
  float* a_d    = (float*)alloc((size_t)N_NODES * 10 * 4);
  float* h1     = (float*)alloc((size_t)N_NODES * 64 * 4);    // 5.12 MB
  float* Wc     = (float*)alloc((size_t)64 * 320 * 4);
  // total ~33.5 MB

  hipMemsetAsync(deg, 0, (size_t)N_NODES * 4, stream);
  hipMemsetAsync(cursor, 0, (size_t)N_NODES * 4, stream);

  int eb = (EP + 255) / 256;
  int nb = (N_NODES + 255) / 256;   // 79
  count_deg_k<<<eb, 256, 0, stream>>>(ei, deg);
  scan1_k<<<nb, 256, 0, stream>>>(deg, offs, bsum);
  scan2_k<<<1, 128, 0, stream>>>(bsum, nb);
  scan3_k<<<nb, 256, 0, stream>>>(offs, bsum);
  scatter_k<<<eb, 256, 0, stream>>>(ei, offs, cursor, ssrc);
  pack23_k<<<40, 256, 0, stream>>>(W2, W3, Wc);

  dim3 gg(313, 5);

  // ---- layer 1 ----
  sgemm_fused_k<64><<<gg, 256, 0, stream>>>(x, W1, xw, att_src1, att_dst1,
                                            nullptr, nullptr, a_s, a_d,
                                            N_NODES, 320, 256);
  agg1_k<<<N_NODES, 320, 0, stream>>>(offs, ssrc, a_s, a_d, xw, b1, h1);

  // ---- layers 2+3 fused ----
  sgemm_fused_k<32><<<gg, 256, 0, stream>>>(h1, Wc, xw, att_src2, att_dst2,
                                            att_src3, att_dst3, a_s, a_d,
                                            N_NODES, 320, 64);
  agg23_k<<<N_NODES, 320, 0, stream>>>(offs, ssrc, a_s, a_d, xw, b2, b3,
                                       out, out + (size_t)N_NODES * 32,
                                       out + (size_t)2 * N_NODES * 32);
}